// Round 1
// baseline (126.552 us; speedup 1.0000x reference)
//
#include <hip/hip_runtime.h>
#include <hip/hip_bf16.h>
#include <stdint.h>

typedef float    f32x4 __attribute__((ext_vector_type(4)));
typedef double   f64x4 __attribute__((ext_vector_type(4)));
typedef _Float16 f16x8 __attribute__((ext_vector_type(8)));

#define NSTEPS 15

// ---------------------------------------------------------------------------
// T[z][2048][512] = embed @ W1[z*512 : z*512+512, :]   (fp64 accumulate)
// ---------------------------------------------------------------------------
__global__ __launch_bounds__(256) void gemm_t_kernel(
    const float* __restrict__ embed,   // [2048][512]
    const float* __restrict__ W1,      // [1024][512]
    double* __restrict__ T)            // [2][2048][512]
{
  const int z  = blockIdx.z;
  const int m0 = blockIdx.x * 64;
  const int n0 = blockIdx.y * 64;
  const int t  = threadIdx.x;

  __shared__ float As[16][64];   // [k][m]
  __shared__ float Bs[16][64];   // [k][n]

  const int tx = t & 15, ty = t >> 4;
  const int ar = t >> 2,  ac = (t & 3) * 4;    // A: row 0..63, k-chunk
  const int bk = t >> 4,  bn = (t & 15) * 4;   // B: k 0..15, n-chunk

  double acc[4][4] = {};

  for (int k0 = 0; k0 < 512; k0 += 16) {
    f32x4 av = *(const f32x4*)&embed[(size_t)(m0 + ar) * 512 + k0 + ac];
    f32x4 bv = *(const f32x4*)&W1[(size_t)(z * 512 + k0 + bk) * 512 + n0 + bn];
    __syncthreads();
#pragma unroll
    for (int j = 0; j < 4; ++j) As[ac + j][ar] = av[j];
    *(f32x4*)&Bs[bk][bn] = bv;
    __syncthreads();
#pragma unroll
    for (int k = 0; k < 16; ++k) {
      f32x4 a = *(const f32x4*)&As[k][ty * 4];
      f32x4 b = *(const f32x4*)&Bs[k][tx * 4];
#pragma unroll
      for (int i = 0; i < 4; ++i)
#pragma unroll
        for (int j = 0; j < 4; ++j)
          acc[i][j] = fma((double)a[i], (double)b[j], acc[i][j]);
    }
  }
#pragma unroll
  for (int i = 0; i < 4; ++i) {
    f64x4 o;
#pragma unroll
    for (int j = 0; j < 4; ++j) o[j] = acc[i][j];
    *(f64x4*)&T[((size_t)z * 2048 + m0 + ty * 4 + i) * 512 + n0 + tx * 4] = o;
  }
}

// ---------------------------------------------------------------------------
// W2 [512][2048] fp32  ->  W2T [2048][512] f16   (tiled transpose + convert)
// ---------------------------------------------------------------------------
__global__ __launch_bounds__(256) void w2t_kernel(
    const float* __restrict__ W2, _Float16* __restrict__ W2T)
{
  __shared__ _Float16 tile[64][72];
  const int n0 = blockIdx.x * 64;
  const int k0 = blockIdx.y * 64;
  const int t  = threadIdx.x;
  const int kk = t >> 4;
  const int n4 = (t & 15) * 4;
#pragma unroll
  for (int i = 0; i < 4; ++i) {
    f32x4 v = *(const f32x4*)&W2[(size_t)(k0 + kk + i * 16) * 2048 + n0 + n4];
#pragma unroll
    for (int j = 0; j < 4; ++j) tile[n4 + j][kk + i * 16] = (_Float16)v[j];
  }
  __syncthreads();
#pragma unroll
  for (int i = 0; i < 2; ++i) {
    const int nn = (t >> 3) + i * 32;
    const int k8 = (t & 7) * 8;
    *(uint4*)&W2T[(size_t)(n0 + nn) * 512 + k0 + k8] = *(const uint4*)&tile[nn][k8];
  }
}

// ---------------------------------------------------------------------------
// bias2s[n] = (sum_{k=0..14} beta2^k) * b2[n]
// ---------------------------------------------------------------------------
__global__ void bias2_kernel(const float* __restrict__ b2,
                             const float* __restrict__ beta2p,
                             float* __restrict__ bias2s)
{
  const float beta2 = fminf(fmaxf(beta2p[0], 0.1f), 0.9f);
  double cb = 0.0;
  for (int i = 0; i < NSTEPS; ++i) cb = (double)beta2 * cb + 1.0;
  const int n = blockIdx.x * 256 + threadIdx.x;
  if (n < 2048) bias2s[n] = (float)(cb * (double)b2[n]);
}

// ---------------------------------------------------------------------------
// Per-element 15-step LIF recurrence -> weighted spike sums S [8192][512] f16
// ---------------------------------------------------------------------------
__global__ __launch_bounds__(256) void recur_kernel(
    const int* __restrict__ x,        // [8192][2]
    const double* __restrict__ T,     // [2][2048][512]
    const float* __restrict__ b1,     // [512]
    const float* __restrict__ beta1p, const float* __restrict__ thr1p,
    const float* __restrict__ beta2p,
    _Float16* __restrict__ S)         // [8192][512]
{
  const double beta1 = (double)fminf(fmaxf(beta1p[0], 0.1f), 0.9f);
  const double thr1  = (double)fmaxf(thr1p[0], 0.1f);
  const double beta2 = (double)fminf(fmaxf(beta2p[0], 0.1f), 0.9f);

  const int t = threadIdx.x;
  const int b = blockIdx.x * 4 + (t >> 6);
  const int h = (t & 63) * 8;
  const int x0 = x[b * 2 + 0];
  const int x1 = x[b * 2 + 1];

  const double* t0 = &T[(size_t)x0 * 512 + h];
  const double* t1 = &T[(size_t)(2048 + x1) * 512 + h];

  double cur[8];
  {
    f64x4 a0 = *(const f64x4*)(t0);
    f64x4 a1 = *(const f64x4*)(t0 + 4);
    f64x4 c0 = *(const f64x4*)(t1);
    f64x4 c1 = *(const f64x4*)(t1 + 4);
    f32x4 e0 = *(const f32x4*)&b1[h];
    f32x4 e1 = *(const f32x4*)&b1[h + 4];
#pragma unroll
    for (int j = 0; j < 4; ++j) {
      cur[j]     = a0[j] + c0[j] + (double)e0[j];
      cur[4 + j] = a1[j] + c1[j] + (double)e1[j];
    }
  }

  double m[8] = {}, s[8] = {};
#pragma unroll
  for (int st = 0; st < NSTEPS; ++st) {
#pragma unroll
    for (int j = 0; j < 8; ++j) {
      // reset uses PREVIOUS mem; spike uses UPDATED mem (snntorch Leaky, subtract)
      double r = (m[j] > thr1) ? thr1 : 0.0;
      m[j] = beta1 * m[j] + cur[j] - r;
      double sp = (m[j] > thr1) ? 1.0 : 0.0;
      s[j] = beta2 * s[j] + sp;   // S = sum_t beta2^{15-t} spk_t
    }
  }

  __align__(16) _Float16 o[8];
#pragma unroll
  for (int j = 0; j < 8; ++j) o[j] = (_Float16)(float)s[j];
  *(uint4*)&S[(size_t)b * 512 + h] = *(const uint4*)o;
}

// ---------------------------------------------------------------------------
// C [8192][2048] = S @ W2T^T + bias2s   (f16 MFMA, 128x128 tile, BK=64)
// ---------------------------------------------------------------------------
__device__ __forceinline__ void gld_lds16(const void* g, void* l) {
  __builtin_amdgcn_global_load_lds(
      (const __attribute__((address_space(1))) uint32_t*)g,
      (__attribute__((address_space(3))) uint32_t*)l, 16, 0, 0);
}

__global__ __launch_bounds__(256) void gemm2_kernel(
    const _Float16* __restrict__ A,    // S   [8192][512]
    const _Float16* __restrict__ Bt,   // W2T [2048][512]
    const float* __restrict__ bias,    // [2048]
    float* __restrict__ C)             // [8192][2048]
{
  __shared__ __align__(16) char lds[32768];
  char* AsB = lds;            // 128 rows x 128B, XOR-swizzled 16B chunks
  char* BsB = lds + 16384;

  const int t    = threadIdx.x;
  const int lane = t & 63;
  const int wave = t >> 6;
  const int wm   = wave >> 1;
  const int wn   = wave & 1;

  int bid = blockIdx.x;
  bid = (bid & 7) * 128 + (bid >> 3);   // XCD swizzle (1024 % 8 == 0, bijective)
  const int m0 = (bid >> 4) * 128;      // 64 m-tiles
  const int n0 = (bid & 15) * 128;      // 16 n-tiles

  f32x4 acc[4][4] = {};

  for (int kt = 0; kt < 8; ++kt) {
    const int k0 = kt * 64;
#pragma unroll
    for (int i = 0; i < 4; ++i) {
      const int ob  = i * 4096 + wave * 1024;  // wave-uniform LDS base
      const int o   = ob + lane * 16;          // this lane's linear slot
      const int row = o >> 7;
      const int cp  = (o >> 4) & 7;
      const int c   = cp ^ (row & 7);          // inverse-swizzled source chunk
      gld_lds16(A  + ((size_t)(m0 + row) * 512 + k0 + c * 8), AsB + ob);
      gld_lds16(Bt + ((size_t)(n0 + row) * 512 + k0 + c * 8), BsB + ob);
    }
    asm volatile("s_waitcnt vmcnt(0)" ::: "memory");
    __syncthreads();

#pragma unroll
    for (int kk = 0; kk < 2; ++kk) {
      const int lc = (lane >> 4) + kk * 4;  // logical chunk = k_elem/8
      f16x8 af[4], bf[4];
#pragma unroll
      for (int mi = 0; mi < 4; ++mi) {
        const int row = wm * 64 + mi * 16 + (lane & 15);
        af[mi] = *(const f16x8*)(AsB + row * 128 + ((lc ^ (row & 7)) << 4));
      }
#pragma unroll
      for (int ni = 0; ni < 4; ++ni) {
        const int row = wn * 64 + ni * 16 + (lane & 15);
        bf[ni] = *(const f16x8*)(BsB + row * 128 + ((lc ^ (row & 7)) << 4));
      }
#pragma unroll
      for (int mi = 0; mi < 4; ++mi)
#pragma unroll
        for (int ni = 0; ni < 4; ++ni)
          acc[mi][ni] = __builtin_amdgcn_mfma_f32_16x16x32_f16(
              af[mi], bf[ni], acc[mi][ni], 0, 0, 0);
    }
    __syncthreads();
  }

  // epilogue: C/D layout col=lane&15, row=(lane>>4)*4+reg
#pragma unroll
  for (int mi = 0; mi < 4; ++mi) {
    const int r0 = m0 + wm * 64 + mi * 16 + ((lane >> 4) << 2);
#pragma unroll
    for (int ni = 0; ni < 4; ++ni) {
      const int cc = n0 + wn * 64 + ni * 16 + (lane & 15);
      const float bv = bias[cc];
#pragma unroll
      for (int q = 0; q < 4; ++q)
        C[(size_t)(r0 + q) * 2048 + cc] = acc[mi][ni][q] + bv;
    }
  }
}

// ---------------------------------------------------------------------------
extern "C" void kernel_launch(void* const* d_in, const int* in_sizes, int n_in,
                              void* d_out, int out_size, void* d_ws, size_t ws_size,
                              hipStream_t stream) {
  const int*   x     = (const int*)  d_in[0];
  const float* embed = (const float*)d_in[1];
  const float* W1    = (const float*)d_in[2];
  const float* b1    = (const float*)d_in[3];
  const float* W2    = (const float*)d_in[4];
  const float* b2    = (const float*)d_in[5];
  const float* beta1 = (const float*)d_in[6];
  const float* thr1  = (const float*)d_in[7];
  const float* beta2 = (const float*)d_in[8];
  // d_in[9] = thr2: clipped but unused by the output
  float* out = (float*)d_out;

  char* ws = (char*)d_ws;
  double*   T      = (double*)ws;                       // 16 MB
  _Float16* W2T    = (_Float16*)(ws + (16u << 20));     //  2 MB
  _Float16* S      = (_Float16*)(ws + (18u << 20));     //  8 MB
  float*    bias2s = (float*)   (ws + (26u << 20));     //  8 KB

  w2t_kernel  <<<dim3(32, 8),    256, 0, stream>>>(W2, W2T);
  bias2_kernel<<<dim3(8),        256, 0, stream>>>(b2, beta2, bias2s);
  gemm_t_kernel<<<dim3(32, 8, 2),256, 0, stream>>>(embed, W1, T);
  recur_kernel<<<dim3(2048),     256, 0, stream>>>(x, T, b1, beta1, thr1, beta2, S);
  gemm2_kernel<<<dim3(1024),     256, 0, stream>>>(S, W2T, bias2s, out);
}

// Round 2
// 89.468 us; speedup vs baseline: 1.4145x; 1.4145x over previous
//
#include <hip/hip_runtime.h>
#include <hip/hip_bf16.h>
#include <stdint.h>

typedef float    f32x4 __attribute__((ext_vector_type(4)));
typedef _Float16 f16x4 __attribute__((ext_vector_type(4)));
typedef _Float16 f16x8 __attribute__((ext_vector_type(8)));

#define NSTEPS 15

// ---------------------------------------------------------------------------
// Split embed [2048][512] f32 into packed f16 A [2048][1536] = [e0 | e1 | e0]
// (two-way Dekker split: e = e0 + e1 + O(2^-23 e))
// ---------------------------------------------------------------------------
__global__ __launch_bounds__(256) void split_e_kernel(
    const float* __restrict__ E, _Float16* __restrict__ Ap)
{
  const int i  = blockIdx.x * 256 + threadIdx.x;   // 2048*512/4 = 262144
  const int m  = i >> 7;
  const int k4 = (i & 127) * 4;
  f32x4 v = *(const f32x4*)&E[(size_t)m * 512 + k4];
  f16x4 h0, h1;
#pragma unroll
  for (int j = 0; j < 4; ++j) {
    h0[j] = (_Float16)v[j];
    h1[j] = (_Float16)(v[j] - (float)h0[j]);
  }
  _Float16* r = Ap + (size_t)m * 1536 + k4;
  *(f16x4*)(r)        = h0;
  *(f16x4*)(r + 512)  = h1;
  *(f16x4*)(r + 1024) = h0;
}

// ---------------------------------------------------------------------------
// W1 [1024][512] f32 -> packed, transposed, 64x-scaled f16 Bt [1024][1536]:
//   Bt[z*512+n][k] = w0, [512+k] = w0, [1024+k] = w1  of  64*W1[z*512+k][n]
// ---------------------------------------------------------------------------
__global__ __launch_bounds__(256) void w1t_split_kernel(
    const float* __restrict__ W1, _Float16* __restrict__ Btp)
{
  __shared__ _Float16 tH[64][72];
  __shared__ _Float16 tL[64][72];
  const int n0 = blockIdx.x * 64;
  const int k0 = blockIdx.y * 64;
  const int z  = blockIdx.z;
  const int t  = threadIdx.x;
  const int kk = t >> 4;
  const int n4 = (t & 15) * 4;
#pragma unroll
  for (int i = 0; i < 4; ++i) {
    f32x4 v = *(const f32x4*)&W1[(size_t)(z * 512 + k0 + kk + i * 16) * 512 + n0 + n4];
#pragma unroll
    for (int j = 0; j < 4; ++j) {
      float s = v[j] * 64.0f;                 // exact pow2 scale
      _Float16 hi = (_Float16)s;
      tH[n4 + j][kk + i * 16] = hi;
      tL[n4 + j][kk + i * 16] = (_Float16)(s - (float)hi);
    }
  }
  __syncthreads();
#pragma unroll
  for (int i = 0; i < 2; ++i) {
    const int nn = (t >> 3) + i * 32;
    const int k8 = (t & 7) * 8;
    _Float16* r = Btp + (size_t)(z * 512 + n0 + nn) * 1536 + k0 + k8;
    uint4 h = *(const uint4*)&tH[nn][k8];
    *(uint4*)(r)        = h;
    *(uint4*)(r + 512)  = h;
    *(uint4*)(r + 1024) = *(const uint4*)&tL[nn][k8];
  }
}

// ---------------------------------------------------------------------------
// W2 [512][2048] fp32  ->  W2T [2048][512] f16   (tiled transpose + convert)
// ---------------------------------------------------------------------------
__global__ __launch_bounds__(256) void w2t_kernel(
    const float* __restrict__ W2, _Float16* __restrict__ W2T)
{
  __shared__ _Float16 tile[64][72];
  const int n0 = blockIdx.x * 64;
  const int k0 = blockIdx.y * 64;
  const int t  = threadIdx.x;
  const int kk = t >> 4;
  const int n4 = (t & 15) * 4;
#pragma unroll
  for (int i = 0; i < 4; ++i) {
    f32x4 v = *(const f32x4*)&W2[(size_t)(k0 + kk + i * 16) * 2048 + n0 + n4];
#pragma unroll
    for (int j = 0; j < 4; ++j) tile[n4 + j][kk + i * 16] = (_Float16)v[j];
  }
  __syncthreads();
#pragma unroll
  for (int i = 0; i < 2; ++i) {
    const int nn = (t >> 3) + i * 32;
    const int k8 = (t & 7) * 8;
    *(uint4*)&W2T[(size_t)(n0 + nn) * 512 + k0 + k8] = *(const uint4*)&tile[nn][k8];
  }
}

// ---------------------------------------------------------------------------
// bias2s[n] = (sum_{k=0..14} beta2^k) * b2[n]
// ---------------------------------------------------------------------------
__global__ void bias2_kernel(const float* __restrict__ b2,
                             const float* __restrict__ beta2p,
                             float* __restrict__ bias2s)
{
  const float beta2 = fminf(fmaxf(beta2p[0], 0.1f), 0.9f);
  float cb = 0.0f;
  for (int i = 0; i < NSTEPS; ++i) cb = beta2 * cb + 1.0f;
  const int n = blockIdx.x * 256 + threadIdx.x;
  if (n < 2048) bias2s[n] = cb * b2[n];
}

// ---------------------------------------------------------------------------
// Per-element 15-step LIF recurrence -> weighted spike sums S [8192][512] f16
// ---------------------------------------------------------------------------
__global__ __launch_bounds__(256) void recur_kernel(
    const int* __restrict__ x,        // [8192][2]
    const float* __restrict__ T,      // [2048][1024]: col z*512+h
    const float* __restrict__ b1,     // [512]
    const float* __restrict__ beta1p, const float* __restrict__ thr1p,
    const float* __restrict__ beta2p,
    _Float16* __restrict__ S)         // [8192][512]
{
  const float beta1 = fminf(fmaxf(beta1p[0], 0.1f), 0.9f);
  const float thr1  = fmaxf(thr1p[0], 0.1f);
  const float beta2 = fminf(fmaxf(beta2p[0], 0.1f), 0.9f);

  const int t = threadIdx.x;
  const int b = blockIdx.x * 4 + (t >> 6);
  const int h = (t & 63) * 8;
  const int x0 = x[b * 2 + 0];
  const int x1 = x[b * 2 + 1];

  const float* t0 = &T[(size_t)x0 * 1024 + h];
  const float* t1 = &T[(size_t)x1 * 1024 + 512 + h];

  float cur[8];
  {
    f32x4 a0 = *(const f32x4*)(t0);
    f32x4 a1 = *(const f32x4*)(t0 + 4);
    f32x4 c0 = *(const f32x4*)(t1);
    f32x4 c1 = *(const f32x4*)(t1 + 4);
    f32x4 e0 = *(const f32x4*)&b1[h];
    f32x4 e1 = *(const f32x4*)&b1[h + 4];
#pragma unroll
    for (int j = 0; j < 4; ++j) {
      cur[j]     = a0[j] + c0[j] + e0[j];
      cur[4 + j] = a1[j] + c1[j] + e1[j];
    }
  }

  float m[8] = {}, s[8] = {};
#pragma unroll
  for (int st = 0; st < NSTEPS; ++st) {
#pragma unroll
    for (int j = 0; j < 8; ++j) {
      // reset uses PREVIOUS mem; spike uses UPDATED mem (snntorch Leaky, subtract)
      float r = (m[j] > thr1) ? thr1 : 0.0f;
      m[j] = beta1 * m[j] + cur[j] - r;
      float sp = (m[j] > thr1) ? 1.0f : 0.0f;
      s[j] = beta2 * s[j] + sp;   // S = sum_t beta2^{15-t} spk_t
    }
  }

  __align__(16) _Float16 o[8];
#pragma unroll
  for (int j = 0; j < 8; ++j) o[j] = (_Float16)s[j];
  *(uint4*)&S[(size_t)b * 512 + h] = *(const uint4*)o;
}

// ---------------------------------------------------------------------------
// Templated f16 MFMA GEMM: C[M][LDC] = scale * (A @ Bt^T) (+ bias)
// 128x128 tile, BK=64, 4 waves x (4x4) 16x16x32 fragments.
// A [M][LDA] f16 row-major, Bt [N][LDB] f16 row-major (B transposed).
// ---------------------------------------------------------------------------
__device__ __forceinline__ void gld_lds16(const void* g, void* l) {
  __builtin_amdgcn_global_load_lds(
      (const __attribute__((address_space(1))) uint32_t*)g,
      (__attribute__((address_space(3))) uint32_t*)l, 16, 0, 0);
}

template<int LDA, int LDB, int LDC, int KTILES, int NTN, bool BIAS>
__global__ __launch_bounds__(256) void mfma_gemm_kernel(
    const _Float16* __restrict__ A, const _Float16* __restrict__ Bt,
    const float* __restrict__ bias, float* __restrict__ C, float scale)
{
  __shared__ __align__(16) char lds[32768];
  char* AsB = lds;            // 128 rows x 128B, XOR-swizzled 16B chunks
  char* BsB = lds + 16384;

  const int t    = threadIdx.x;
  const int lane = t & 63;
  const int wave = t >> 6;
  const int wm   = wave >> 1;
  const int wn   = wave & 1;

  int bid = blockIdx.x;
  bid = (bid & 7) * (gridDim.x >> 3) + (bid >> 3);  // XCD swizzle (nwg%8==0)
  const int m0 = (bid / NTN) * 128;
  const int n0 = (bid % NTN) * 128;

  f32x4 acc[4][4] = {};

  for (int kt = 0; kt < KTILES; ++kt) {
    const int k0 = kt * 64;
#pragma unroll
    for (int i = 0; i < 4; ++i) {
      const int ob  = i * 4096 + wave * 1024;  // wave-uniform LDS base
      const int o   = ob + lane * 16;          // this lane's linear slot
      const int row = o >> 7;
      const int cp  = (o >> 4) & 7;
      const int c   = cp ^ (row & 7);          // inverse-swizzled source chunk
      gld_lds16(A  + ((size_t)(m0 + row) * LDA + k0 + c * 8), AsB + ob);
      gld_lds16(Bt + ((size_t)(n0 + row) * LDB + k0 + c * 8), BsB + ob);
    }
    asm volatile("s_waitcnt vmcnt(0)" ::: "memory");
    __syncthreads();

#pragma unroll
    for (int kk = 0; kk < 2; ++kk) {
      const int lc = (lane >> 4) + kk * 4;  // logical chunk = k_elem/8
      f16x8 af[4], bf[4];
#pragma unroll
      for (int mi = 0; mi < 4; ++mi) {
        const int row = wm * 64 + mi * 16 + (lane & 15);
        af[mi] = *(const f16x8*)(AsB + row * 128 + ((lc ^ (row & 7)) << 4));
      }
#pragma unroll
      for (int ni = 0; ni < 4; ++ni) {
        const int row = wn * 64 + ni * 16 + (lane & 15);
        bf[ni] = *(const f16x8*)(BsB + row * 128 + ((lc ^ (row & 7)) << 4));
      }
#pragma unroll
      for (int mi = 0; mi < 4; ++mi)
#pragma unroll
        for (int ni = 0; ni < 4; ++ni)
          acc[mi][ni] = __builtin_amdgcn_mfma_f32_16x16x32_f16(
              af[mi], bf[ni], acc[mi][ni], 0, 0, 0);
    }
    __syncthreads();
  }

  // epilogue: C/D layout col=lane&15, row=(lane>>4)*4+reg
#pragma unroll
  for (int mi = 0; mi < 4; ++mi) {
    const int r0 = m0 + wm * 64 + mi * 16 + ((lane >> 4) << 2);
#pragma unroll
    for (int ni = 0; ni < 4; ++ni) {
      const int cc = n0 + wn * 64 + ni * 16 + (lane & 15);
      const float bv = BIAS ? bias[cc] : 0.0f;
#pragma unroll
      for (int q = 0; q < 4; ++q)
        C[(size_t)(r0 + q) * LDC + cc] = acc[mi][ni][q] * scale + bv;
    }
  }
}

// ---------------------------------------------------------------------------
extern "C" void kernel_launch(void* const* d_in, const int* in_sizes, int n_in,
                              void* d_out, int out_size, void* d_ws, size_t ws_size,
                              hipStream_t stream) {
  const int*   x     = (const int*)  d_in[0];
  const float* embed = (const float*)d_in[1];
  const float* W1    = (const float*)d_in[2];
  const float* b1    = (const float*)d_in[3];
  const float* W2    = (const float*)d_in[4];
  const float* b2    = (const float*)d_in[5];
  const float* beta1 = (const float*)d_in[6];
  const float* thr1  = (const float*)d_in[7];
  const float* beta2 = (const float*)d_in[8];
  // d_in[9] = thr2: clipped but unused by the output
  float* out = (float*)d_out;

  char* ws = (char*)d_ws;
  _Float16* Ap     = (_Float16*)ws;                     //  6 MB [2048][1536]
  _Float16* Btp    = (_Float16*)(ws + ( 6u << 20));     //  3 MB [1024][1536]
  float*    T      = (float*)   (ws + ( 9u << 20));     //  8 MB [2048][1024]
  _Float16* W2T    = (_Float16*)(ws + (17u << 20));     //  2 MB [2048][512]
  _Float16* S      = (_Float16*)(ws + (19u << 20));     //  8 MB [8192][512]
  float*    bias2s = (float*)   (ws + (27u << 20));     //  8 KB

  split_e_kernel  <<<dim3(1024),    256, 0, stream>>>(embed, Ap);
  w1t_split_kernel<<<dim3(8, 8, 2), 256, 0, stream>>>(W1, Btp);
  w2t_kernel      <<<dim3(32, 8),   256, 0, stream>>>(W2, W2T);
  bias2_kernel    <<<dim3(8),       256, 0, stream>>>(b2, beta2, bias2s);

  // T[m][z*512+n] = embed @ W1 (two-way f16 split, 3 cross terms, K=1536)
  mfma_gemm_kernel<1536, 1536, 1024, 24, 8, false>
      <<<dim3(128), 256, 0, stream>>>(Ap, Btp, nullptr, T, 1.0f / 64.0f);

  recur_kernel<<<dim3(2048), 256, 0, stream>>>(x, T, b1, beta1, thr1, beta2, S);

  // out = S @ W2 + cb*b2
  mfma_gemm_kernel<512, 512, 2048, 8, 16, true>
      <<<dim3(1024), 256, 0, stream>>>(S, W2T, bias2s, out, 1.0f);
}

// Round 3
// 71.935 us; speedup vs baseline: 1.7593x; 1.2437x over previous
//
#include <hip/hip_runtime.h>
#include <hip/hip_bf16.h>
#include <stdint.h>

typedef float    f32x4 __attribute__((ext_vector_type(4)));
typedef _Float16 f16x4 __attribute__((ext_vector_type(4)));
typedef _Float16 f16x8 __attribute__((ext_vector_type(8)));

#define NSTEPS 15

// ---------------------------------------------------------------------------
// Fused prep kernel, block-range dispatch:
//   [0,1024)    split_e : embed [2048][512] f32 -> Ap [2048][1536] f16 = [e0|e1|e0]
//   [1024,1152) w1t     : W1 [1024][512] f32 -> Btp [1024][1536] f16 (T, 64x, split)
//   [1152,1408) w2t     : W2 [512][2048] f32 -> W2T [2048][512] f16 (T)
//   [1408,1416) bias2   : bias2s[n] = (sum beta2^k) * b2[n]
// ---------------------------------------------------------------------------
__global__ __launch_bounds__(256) void prep_kernel(
    const float* __restrict__ embed, const float* __restrict__ W1,
    const float* __restrict__ W2, const float* __restrict__ b2,
    const float* __restrict__ beta2p,
    _Float16* __restrict__ Ap, _Float16* __restrict__ Btp,
    _Float16* __restrict__ W2T, float* __restrict__ bias2s)
{
  __shared__ _Float16 sh[2][64][72];
  const int b = blockIdx.x;
  const int t = threadIdx.x;

  if (b < 1024) {                       // ---- split_e (Dekker two-way split)
    const int i  = b * 256 + t;
    const int m  = i >> 7;
    const int k4 = (i & 127) * 4;
    f32x4 v = *(const f32x4*)&embed[(size_t)m * 512 + k4];
    f16x4 h0, h1;
#pragma unroll
    for (int j = 0; j < 4; ++j) {
      h0[j] = (_Float16)v[j];
      h1[j] = (_Float16)(v[j] - (float)h0[j]);
    }
    _Float16* r = Ap + (size_t)m * 1536 + k4;
    *(f16x4*)(r)        = h0;
    *(f16x4*)(r + 512)  = h1;
    *(f16x4*)(r + 1024) = h0;
  } else if (b < 1152) {                // ---- w1t_split (transpose + 64x + split)
    const int idx = b - 1024;
    const int n0 = (idx & 7) * 64;
    const int k0 = ((idx >> 3) & 7) * 64;
    const int z  = idx >> 6;
    const int kk = t >> 4;
    const int n4 = (t & 15) * 4;
#pragma unroll
    for (int i = 0; i < 4; ++i) {
      f32x4 v = *(const f32x4*)&W1[(size_t)(z * 512 + k0 + kk + i * 16) * 512 + n0 + n4];
#pragma unroll
      for (int j = 0; j < 4; ++j) {
        float s = v[j] * 64.0f;         // exact pow2 scale
        _Float16 hi = (_Float16)s;
        sh[0][n4 + j][kk + i * 16] = hi;
        sh[1][n4 + j][kk + i * 16] = (_Float16)(s - (float)hi);
      }
    }
    __syncthreads();
#pragma unroll
    for (int i = 0; i < 2; ++i) {
      const int nn = (t >> 3) + i * 32;
      const int k8 = (t & 7) * 8;
      _Float16* r = Btp + (size_t)(z * 512 + n0 + nn) * 1536 + k0 + k8;
      uint4 h = *(const uint4*)&sh[0][nn][k8];
      *(uint4*)(r)        = h;
      *(uint4*)(r + 512)  = h;
      *(uint4*)(r + 1024) = *(const uint4*)&sh[1][nn][k8];
    }
  } else if (b < 1408) {                // ---- w2t (transpose + f16 convert)
    const int idx = b - 1152;
    const int n0 = (idx & 31) * 64;
    const int k0 = (idx >> 5) * 64;
    const int kk = t >> 4;
    const int n4 = (t & 15) * 4;
#pragma unroll
    for (int i = 0; i < 4; ++i) {
      f32x4 v = *(const f32x4*)&W2[(size_t)(k0 + kk + i * 16) * 2048 + n0 + n4];
#pragma unroll
      for (int j = 0; j < 4; ++j) sh[0][n4 + j][kk + i * 16] = (_Float16)v[j];
    }
    __syncthreads();
#pragma unroll
    for (int i = 0; i < 2; ++i) {
      const int nn = (t >> 3) + i * 32;
      const int k8 = (t & 7) * 8;
      *(uint4*)&W2T[(size_t)(n0 + nn) * 512 + k0 + k8] = *(const uint4*)&sh[0][nn][k8];
    }
  } else {                              // ---- bias2
    const float beta2 = fminf(fmaxf(beta2p[0], 0.1f), 0.9f);
    float cb = 0.0f;
    for (int i = 0; i < NSTEPS; ++i) cb = beta2 * cb + 1.0f;
    const int n = (b - 1408) * 256 + t;
    if (n < 2048) bias2s[n] = cb * b2[n];
  }
}

// ---------------------------------------------------------------------------
// Per-element 15-step LIF recurrence -> weighted spike sums S [8192][512] f16
// ---------------------------------------------------------------------------
__global__ __launch_bounds__(256) void recur_kernel(
    const int* __restrict__ x,        // [8192][2]
    const float* __restrict__ T,      // [2048][1024]: col z*512+h
    const float* __restrict__ b1,     // [512]
    const float* __restrict__ beta1p, const float* __restrict__ thr1p,
    const float* __restrict__ beta2p,
    _Float16* __restrict__ S)         // [8192][512]
{
  const float beta1 = fminf(fmaxf(beta1p[0], 0.1f), 0.9f);
  const float thr1  = fmaxf(thr1p[0], 0.1f);
  const float beta2 = fminf(fmaxf(beta2p[0], 0.1f), 0.9f);

  const int t = threadIdx.x;
  const int b = blockIdx.x * 4 + (t >> 6);
  const int h = (t & 63) * 8;
  const int x0 = x[b * 2 + 0];
  const int x1 = x[b * 2 + 1];

  const float* t0 = &T[(size_t)x0 * 1024 + h];
  const float* t1 = &T[(size_t)x1 * 1024 + 512 + h];

  float cur[8];
  {
    f32x4 a0 = *(const f32x4*)(t0);
    f32x4 a1 = *(const f32x4*)(t0 + 4);
    f32x4 c0 = *(const f32x4*)(t1);
    f32x4 c1 = *(const f32x4*)(t1 + 4);
    f32x4 e0 = *(const f32x4*)&b1[h];
    f32x4 e1 = *(const f32x4*)&b1[h + 4];
#pragma unroll
    for (int j = 0; j < 4; ++j) {
      cur[j]     = a0[j] + c0[j] + e0[j];
      cur[4 + j] = a1[j] + c1[j] + e1[j];
    }
  }

  float m[8] = {}, s[8] = {};
#pragma unroll
  for (int st = 0; st < NSTEPS; ++st) {
#pragma unroll
    for (int j = 0; j < 8; ++j) {
      // reset uses PREVIOUS mem; spike uses UPDATED mem (snntorch Leaky, subtract)
      float r = (m[j] > thr1) ? thr1 : 0.0f;
      m[j] = beta1 * m[j] + cur[j] - r;
      float sp = (m[j] > thr1) ? 1.0f : 0.0f;
      s[j] = beta2 * s[j] + sp;   // S = sum_t beta2^{15-t} spk_t
    }
  }

  __align__(16) _Float16 o[8];
#pragma unroll
  for (int j = 0; j < 8; ++j) o[j] = (_Float16)s[j];
  *(uint4*)&S[(size_t)b * 512 + h] = *(const uint4*)o;
}

// ---------------------------------------------------------------------------
// Templated f16 MFMA GEMM: C[M][LDC] = scale * (A @ Bt^T) (+ bias)
// BMxBN tile, BK=64, 4 waves (WM_ x WN_), FMxFN 16x16x32 fragments per wave.
// A [M][LDA] f16 row-major, Bt [N][LDB] f16 row-major (B transposed).
// LDS: XOR-swizzled 16B chunks within 128B rows; linear global_load_lds dest
// with inverse-swizzled global source (both-sides swizzle, G21).
// ---------------------------------------------------------------------------
__device__ __forceinline__ void gld_lds16(const void* g, void* l) {
  __builtin_amdgcn_global_load_lds(
      (const __attribute__((address_space(1))) uint32_t*)g,
      (__attribute__((address_space(3))) uint32_t*)l, 16, 0, 0);
}

template<int BM, int BN, int WM_, int WN_, int LDA, int LDB, int LDC,
         int KTILES, int NTN, bool BIAS>
__global__ __launch_bounds__(256) void mfma_gemm_kernel(
    const _Float16* __restrict__ A, const _Float16* __restrict__ Bt,
    const float* __restrict__ bias, float* __restrict__ C, float scale)
{
  constexpr int FM  = BM / (WM_ * 16);   // fragment rows per wave
  constexpr int FN  = BN / (WN_ * 16);   // fragment cols per wave
  constexpr int ITA = BM / 32;           // A staging iters (BM*128B / 4096B)
  constexpr int ITB = BN / 32;           // B staging iters

  __shared__ __align__(16) char lds[BM * 128 + BN * 128];
  char* AsB = lds;             // BM rows x 128B
  char* BsB = lds + BM * 128;  // BN rows x 128B

  const int t    = threadIdx.x;
  const int lane = t & 63;
  const int wave = t >> 6;
  const int wm   = wave / WN_;
  const int wn   = wave % WN_;

  int bid = blockIdx.x;
  bid = (bid & 7) * (gridDim.x >> 3) + (bid >> 3);  // XCD swizzle (nwg%8==0)
  const int m0 = (bid / NTN) * BM;
  const int n0 = (bid % NTN) * BN;

  f32x4 acc[FM][FN] = {};

  for (int kt = 0; kt < KTILES; ++kt) {
    const int k0 = kt * 64;
#pragma unroll
    for (int i = 0; i < ITA; ++i) {
      const int ob  = i * 4096 + wave * 1024;  // wave-uniform LDS base
      const int o   = ob + lane * 16;          // this lane's linear slot
      const int row = o >> 7;
      const int c   = ((o >> 4) & 7) ^ (row & 7);  // inverse-swizzled source
      gld_lds16(A + ((size_t)(m0 + row) * LDA + k0 + c * 8), AsB + ob);
    }
#pragma unroll
    for (int i = 0; i < ITB; ++i) {
      const int ob  = i * 4096 + wave * 1024;
      const int o   = ob + lane * 16;
      const int row = o >> 7;
      const int c   = ((o >> 4) & 7) ^ (row & 7);
      gld_lds16(Bt + ((size_t)(n0 + row) * LDB + k0 + c * 8), BsB + ob);
    }
    asm volatile("s_waitcnt vmcnt(0)" ::: "memory");
    __syncthreads();

#pragma unroll
    for (int kk = 0; kk < 2; ++kk) {
      const int lc = (lane >> 4) + kk * 4;  // logical chunk = k_elem/8
      f16x8 af[FM], bf[FN];
#pragma unroll
      for (int mi = 0; mi < FM; ++mi) {
        const int row = wm * (FM * 16) + mi * 16 + (lane & 15);
        af[mi] = *(const f16x8*)(AsB + row * 128 + ((lc ^ (row & 7)) << 4));
      }
#pragma unroll
      for (int ni = 0; ni < FN; ++ni) {
        const int row = wn * (FN * 16) + ni * 16 + (lane & 15);
        bf[ni] = *(const f16x8*)(BsB + row * 128 + ((lc ^ (row & 7)) << 4));
      }
#pragma unroll
      for (int mi = 0; mi < FM; ++mi)
#pragma unroll
        for (int ni = 0; ni < FN; ++ni)
          acc[mi][ni] = __builtin_amdgcn_mfma_f32_16x16x32_f16(
              af[mi], bf[ni], acc[mi][ni], 0, 0, 0);
    }
    __syncthreads();
  }

  // epilogue: C/D layout col=lane&15, row=(lane>>4)*4+reg
#pragma unroll
  for (int mi = 0; mi < FM; ++mi) {
    const int r0 = m0 + wm * (FM * 16) + mi * 16 + ((lane >> 4) << 2);
#pragma unroll
    for (int ni = 0; ni < FN; ++ni) {
      const int cc = n0 + wn * (FN * 16) + ni * 16 + (lane & 15);
      const float bv = BIAS ? bias[cc] : 0.0f;
#pragma unroll
      for (int q = 0; q < 4; ++q)
        C[(size_t)(r0 + q) * LDC + cc] = acc[mi][ni][q] * scale + bv;
    }
  }
}

// ---------------------------------------------------------------------------
extern "C" void kernel_launch(void* const* d_in, const int* in_sizes, int n_in,
                              void* d_out, int out_size, void* d_ws, size_t ws_size,
                              hipStream_t stream) {
  const int*   x     = (const int*)  d_in[0];
  const float* embed = (const float*)d_in[1];
  const float* W1    = (const float*)d_in[2];
  const float* b1    = (const float*)d_in[3];
  const float* W2    = (const float*)d_in[4];
  const float* b2    = (const float*)d_in[5];
  const float* beta1 = (const float*)d_in[6];
  const float* thr1  = (const float*)d_in[7];
  const float* beta2 = (const float*)d_in[8];
  // d_in[9] = thr2: clipped but unused by the output
  float* out = (float*)d_out;

  char* ws = (char*)d_ws;
  _Float16* Ap     = (_Float16*)ws;                     //  6 MB [2048][1536]
  _Float16* Btp    = (_Float16*)(ws + ( 6u << 20));     //  3 MB [1024][1536]
  float*    T      = (float*)   (ws + ( 9u << 20));     //  8 MB [2048][1024]
  _Float16* W2T    = (_Float16*)(ws + (17u << 20));     //  2 MB [2048][512]
  _Float16* S      = (_Float16*)(ws + (19u << 20));     //  8 MB [8192][512]
  float*    bias2s = (float*)   (ws + (27u << 20));     //  8 KB

  prep_kernel<<<dim3(1416), 256, 0, stream>>>(embed, W1, W2, b2, beta2,
                                              Ap, Btp, W2T, bias2s);

  // T[m][z*512+n] = embed @ W1 (two-way f16 split, 3 cross terms, K=1536)
  // 128x64 tile, 4x1 waves -> 256 blocks (1/CU)
  mfma_gemm_kernel<128, 64, 4, 1, 1536, 1536, 1024, 24, 16, false>
      <<<dim3(256), 256, 0, stream>>>(Ap, Btp, nullptr, T, 1.0f / 64.0f);

  recur_kernel<<<dim3(2048), 256, 0, stream>>>(x, T, b1, beta1, thr1, beta2, S);

  // out = S @ W2 + cb*b2   (128x128 tile, 2x2 waves, 1024 blocks)
  mfma_gemm_kernel<128, 128, 2, 2, 512, 512, 2048, 8, 16, true>
      <<<dim3(1024), 256, 0, stream>>>(S, W2T, bias2s, out, 1.0f);
}

// Round 4
// 65.707 us; speedup vs baseline: 1.9260x; 1.0948x over previous
//
#include <hip/hip_runtime.h>
#include <hip/hip_bf16.h>
#include <stdint.h>

typedef float    f32x4 __attribute__((ext_vector_type(4)));
typedef _Float16 f16x4 __attribute__((ext_vector_type(4)));
typedef _Float16 f16x8 __attribute__((ext_vector_type(8)));

#define NSTEPS 15

// ---------------------------------------------------------------------------
// Fused prep kernel, block-range dispatch:
//   [0,1024)    split_e : embed [2048][512] f32 -> Ap [2048][1024] f16 = [e0|e1]
//   [1024,1152) w1t     : W1 [1024][512] f32 -> Btp [1024][1024] f16 (T, 64x, split)
//   [1152,1408) w2t     : W2 [512][2048] f32 -> W2T [2048][512] f16 (T)
//   [1408,1416) bias2   : bias2s[n] = (sum beta2^k) * b2[n]
// ---------------------------------------------------------------------------
__global__ __launch_bounds__(256) void prep_kernel(
    const float* __restrict__ embed, const float* __restrict__ W1,
    const float* __restrict__ W2, const float* __restrict__ b2,
    const float* __restrict__ beta2p,
    _Float16* __restrict__ Ap, _Float16* __restrict__ Btp,
    _Float16* __restrict__ W2T, float* __restrict__ bias2s)
{
  __shared__ _Float16 sh[2][64][72];
  const int b = blockIdx.x;
  const int t = threadIdx.x;

  if (b < 1024) {                       // ---- split_e (Dekker two-way split)
    const int i  = b * 256 + t;
    const int m  = i >> 7;
    const int k4 = (i & 127) * 4;
    f32x4 v = *(const f32x4*)&embed[(size_t)m * 512 + k4];
    f16x4 h0, h1;
#pragma unroll
    for (int j = 0; j < 4; ++j) {
      h0[j] = (_Float16)v[j];
      h1[j] = (_Float16)(v[j] - (float)h0[j]);
    }
    _Float16* r = Ap + (size_t)m * 1024 + k4;
    *(f16x4*)(r)       = h0;
    *(f16x4*)(r + 512) = h1;
  } else if (b < 1152) {                // ---- w1t_split (transpose + 64x + split)
    const int idx = b - 1024;
    const int n0 = (idx & 7) * 64;
    const int k0 = ((idx >> 3) & 7) * 64;
    const int z  = idx >> 6;
    const int kk = t >> 4;
    const int n4 = (t & 15) * 4;
#pragma unroll
    for (int i = 0; i < 4; ++i) {
      f32x4 v = *(const f32x4*)&W1[(size_t)(z * 512 + k0 + kk + i * 16) * 512 + n0 + n4];
#pragma unroll
      for (int j = 0; j < 4; ++j) {
        float s = v[j] * 64.0f;         // exact pow2 scale
        _Float16 hi = (_Float16)s;
        sh[0][n4 + j][kk + i * 16] = hi;
        sh[1][n4 + j][kk + i * 16] = (_Float16)(s - (float)hi);
      }
    }
    __syncthreads();
#pragma unroll
    for (int i = 0; i < 2; ++i) {
      const int nn = (t >> 3) + i * 32;
      const int k8 = (t & 7) * 8;
      _Float16* r = Btp + (size_t)(z * 512 + n0 + nn) * 1024 + k0 + k8;
      *(uint4*)(r)       = *(const uint4*)&sh[0][nn][k8];
      *(uint4*)(r + 512) = *(const uint4*)&sh[1][nn][k8];
    }
  } else if (b < 1408) {                // ---- w2t (transpose + f16 convert)
    const int idx = b - 1152;
    const int n0 = (idx & 31) * 64;
    const int k0 = (idx >> 5) * 64;
    const int kk = t >> 4;
    const int n4 = (t & 15) * 4;
#pragma unroll
    for (int i = 0; i < 4; ++i) {
      f32x4 v = *(const f32x4*)&W2[(size_t)(k0 + kk + i * 16) * 2048 + n0 + n4];
#pragma unroll
      for (int j = 0; j < 4; ++j) sh[0][n4 + j][kk + i * 16] = (_Float16)v[j];
    }
    __syncthreads();
#pragma unroll
    for (int i = 0; i < 2; ++i) {
      const int nn = (t >> 3) + i * 32;
      const int k8 = (t & 7) * 8;
      *(uint4*)&W2T[(size_t)(n0 + nn) * 512 + k0 + k8] = *(const uint4*)&sh[0][nn][k8];
    }
  } else {                              // ---- bias2
    const float beta2 = fminf(fmaxf(beta2p[0], 0.1f), 0.9f);
    float cb = 0.0f;
    for (int i = 0; i < NSTEPS; ++i) cb = beta2 * cb + 1.0f;
    const int n = (b - 1408) * 256 + t;
    if (n < 2048) bias2s[n] = cb * b2[n];
  }
}

// ---------------------------------------------------------------------------
__device__ __forceinline__ void gld_lds16(const void* g, void* l) {
  __builtin_amdgcn_global_load_lds(
      (const __attribute__((address_space(1))) uint32_t*)g,
      (__attribute__((address_space(3))) uint32_t*)l, 16, 0, 0);
}

// ---------------------------------------------------------------------------
// gemm1: Tp[z] = (1/64) * Ap @ Btp^T over virtual K-range [z*768,(z+1)*768)
// Virtual K=1536 = [e0w0 | e1w0 | e0w1] resolved via column maps:
//   acol(k) = k<1024 ? k : k-1024 ;  bcol(k) = k<1024 ? (k&511) : k-512
// 128x64 tile, 4x1 waves, FM=2, FN=4. Grid (256, 2) -> 2 blocks/CU.
// ---------------------------------------------------------------------------
__global__ __launch_bounds__(256) void gemm1_kernel(
    const _Float16* __restrict__ Ap,   // [2048][1024]
    const _Float16* __restrict__ Btp,  // [1024][1024]
    float* __restrict__ Tp)            // [2][2048][1024]
{
  __shared__ __align__(16) char lds[(128 + 64) * 128];
  char* AsB = lds;              // 128 rows x 128B, XOR-swizzled 16B chunks
  char* BsB = lds + 128 * 128;  //  64 rows x 128B

  const int t    = threadIdx.x;
  const int lane = t & 63;
  const int wave = t >> 6;      // wm = wave (4x1), wn = 0
  const int z    = blockIdx.y;

  int bid = blockIdx.x;
  bid = (bid & 7) * 32 + (bid >> 3);   // XCD swizzle (256 % 8 == 0)
  const int m0 = (bid >> 4) * 128;     // 16 m-tiles
  const int n0 = (bid & 15) * 64;      // 16 n-tiles

  f32x4 acc[2][4] = {};

  for (int kt = 0; kt < 12; ++kt) {
    const int k0   = z * 768 + kt * 64;
    const int acol = (k0 < 1024) ? k0 : k0 - 1024;
    const int bcol = (k0 < 1024) ? (k0 & 511) : k0 - 512;
#pragma unroll
    for (int i = 0; i < 4; ++i) {      // A: 128 rows
      const int ob  = i * 4096 + wave * 1024;
      const int o   = ob + lane * 16;
      const int row = o >> 7;
      const int c   = ((o >> 4) & 7) ^ (row & 7);
      gld_lds16(Ap + ((size_t)(m0 + row) * 1024 + acol + c * 8), AsB + ob);
    }
#pragma unroll
    for (int i = 0; i < 2; ++i) {      // B: 64 rows
      const int ob  = i * 4096 + wave * 1024;
      const int o   = ob + lane * 16;
      const int row = o >> 7;
      const int c   = ((o >> 4) & 7) ^ (row & 7);
      gld_lds16(Btp + ((size_t)(n0 + row) * 1024 + bcol + c * 8), BsB + ob);
    }
    asm volatile("s_waitcnt vmcnt(0)" ::: "memory");
    __syncthreads();

#pragma unroll
    for (int kk = 0; kk < 2; ++kk) {
      const int lc = (lane >> 4) + kk * 4;
      f16x8 af[2], bf[4];
#pragma unroll
      for (int mi = 0; mi < 2; ++mi) {
        const int row = wave * 32 + mi * 16 + (lane & 15);
        af[mi] = *(const f16x8*)(AsB + row * 128 + ((lc ^ (row & 7)) << 4));
      }
#pragma unroll
      for (int ni = 0; ni < 4; ++ni) {
        const int row = ni * 16 + (lane & 15);
        bf[ni] = *(const f16x8*)(BsB + row * 128 + ((lc ^ (row & 7)) << 4));
      }
#pragma unroll
      for (int mi = 0; mi < 2; ++mi)
#pragma unroll
        for (int ni = 0; ni < 4; ++ni)
          acc[mi][ni] = __builtin_amdgcn_mfma_f32_16x16x32_f16(
              af[mi], bf[ni], acc[mi][ni], 0, 0, 0);
    }
    __syncthreads();
  }

  float* Cz = Tp + (size_t)z * 2048 * 1024;
#pragma unroll
  for (int mi = 0; mi < 2; ++mi) {
    const int r0 = m0 + wave * 32 + mi * 16 + ((lane >> 4) << 2);
#pragma unroll
    for (int ni = 0; ni < 4; ++ni) {
      const int cc = n0 + ni * 16 + (lane & 15);
#pragma unroll
      for (int q = 0; q < 4; ++q)
        Cz[(size_t)(r0 + q) * 1024 + cc] = acc[mi][ni][q] * 0.015625f;
    }
  }
}

// ---------------------------------------------------------------------------
// Per-element 15-step LIF recurrence -> weighted spike sums S [8192][512] f16
// cur1 = Tp0[x0] + Tp1[x0] (+512-offset slices for x1) + b1
// ---------------------------------------------------------------------------
__global__ __launch_bounds__(256) void recur_kernel(
    const int* __restrict__ x,        // [8192][2]
    const float* __restrict__ Tp,     // [2][2048][1024]
    const float* __restrict__ b1,     // [512]
    const float* __restrict__ beta1p, const float* __restrict__ thr1p,
    const float* __restrict__ beta2p,
    _Float16* __restrict__ S)         // [8192][512]
{
  const float beta1 = fminf(fmaxf(beta1p[0], 0.1f), 0.9f);
  const float thr1  = fmaxf(thr1p[0], 0.1f);
  const float beta2 = fminf(fmaxf(beta2p[0], 0.1f), 0.9f);
  const size_t ZS = (size_t)2048 * 1024;

  const int t = threadIdx.x;
  const int b = blockIdx.x * 4 + (t >> 6);
  const int h = (t & 63) * 8;
  const int x0 = x[b * 2 + 0];
  const int x1 = x[b * 2 + 1];

  const float* p00 = &Tp[(size_t)x0 * 1024 + h];
  const float* p01 = &Tp[(size_t)x1 * 1024 + 512 + h];

  float cur[8];
#pragma unroll
  for (int half = 0; half < 2; ++half) {
    f32x4 a0 = *(const f32x4*)(p00 + half * 4);
    f32x4 a1 = *(const f32x4*)(p00 + ZS + half * 4);
    f32x4 c0 = *(const f32x4*)(p01 + half * 4);
    f32x4 c1 = *(const f32x4*)(p01 + ZS + half * 4);
    f32x4 e  = *(const f32x4*)&b1[h + half * 4];
#pragma unroll
    for (int j = 0; j < 4; ++j)
      cur[half * 4 + j] = (a0[j] + a1[j]) + (c0[j] + c1[j]) + e[j];
  }

  float m[8] = {}, s[8] = {};
#pragma unroll
  for (int st = 0; st < NSTEPS; ++st) {
#pragma unroll
    for (int j = 0; j < 8; ++j) {
      // reset uses PREVIOUS mem; spike uses UPDATED mem (snntorch Leaky, subtract)
      float r = (m[j] > thr1) ? thr1 : 0.0f;
      m[j] = beta1 * m[j] + cur[j] - r;
      float sp = (m[j] > thr1) ? 1.0f : 0.0f;
      s[j] = beta2 * s[j] + sp;   // S = sum_t beta2^{15-t} spk_t
    }
  }

  __align__(16) _Float16 o[8];
#pragma unroll
  for (int j = 0; j < 8; ++j) o[j] = (_Float16)s[j];
  *(uint4*)&S[(size_t)b * 512 + h] = *(const uint4*)o;
}

// ---------------------------------------------------------------------------
// Templated f16 MFMA GEMM (gemm2): C[M][LDC] = scale * (A @ Bt^T) (+ bias)
// BMxBN tile, BK=64, 4 waves (WM_ x WN_), FMxFN 16x16x32 fragments per wave.
// ---------------------------------------------------------------------------
template<int BM, int BN, int WM_, int WN_, int LDA, int LDB, int LDC,
         int KTILES, int NTN, bool BIAS>
__global__ __launch_bounds__(256) void mfma_gemm_kernel(
    const _Float16* __restrict__ A, const _Float16* __restrict__ Bt,
    const float* __restrict__ bias, float* __restrict__ C, float scale)
{
  constexpr int FM  = BM / (WM_ * 16);
  constexpr int FN  = BN / (WN_ * 16);
  constexpr int ITA = BM / 32;
  constexpr int ITB = BN / 32;

  __shared__ __align__(16) char lds[BM * 128 + BN * 128];
  char* AsB = lds;
  char* BsB = lds + BM * 128;

  const int t    = threadIdx.x;
  const int lane = t & 63;
  const int wave = t >> 6;
  const int wm   = wave / WN_;
  const int wn   = wave % WN_;

  int bid = blockIdx.x;
  bid = (bid & 7) * (gridDim.x >> 3) + (bid >> 3);  // XCD swizzle (nwg%8==0)
  const int m0 = (bid / NTN) * BM;
  const int n0 = (bid % NTN) * BN;

  f32x4 acc[FM][FN] = {};

  for (int kt = 0; kt < KTILES; ++kt) {
    const int k0 = kt * 64;
#pragma unroll
    for (int i = 0; i < ITA; ++i) {
      const int ob  = i * 4096 + wave * 1024;
      const int o   = ob + lane * 16;
      const int row = o >> 7;
      const int c   = ((o >> 4) & 7) ^ (row & 7);
      gld_lds16(A + ((size_t)(m0 + row) * LDA + k0 + c * 8), AsB + ob);
    }
#pragma unroll
    for (int i = 0; i < ITB; ++i) {
      const int ob  = i * 4096 + wave * 1024;
      const int o   = ob + lane * 16;
      const int row = o >> 7;
      const int c   = ((o >> 4) & 7) ^ (row & 7);
      gld_lds16(Bt + ((size_t)(n0 + row) * LDB + k0 + c * 8), BsB + ob);
    }
    asm volatile("s_waitcnt vmcnt(0)" ::: "memory");
    __syncthreads();

#pragma unroll
    for (int kk = 0; kk < 2; ++kk) {
      const int lc = (lane >> 4) + kk * 4;
      f16x8 af[FM], bf[FN];
#pragma unroll
      for (int mi = 0; mi < FM; ++mi) {
        const int row = wm * (FM * 16) + mi * 16 + (lane & 15);
        af[mi] = *(const f16x8*)(AsB + row * 128 + ((lc ^ (row & 7)) << 4));
      }
#pragma unroll
      for (int ni = 0; ni < FN; ++ni) {
        const int row = wn * (FN * 16) + ni * 16 + (lane & 15);
        bf[ni] = *(const f16x8*)(BsB + row * 128 + ((lc ^ (row & 7)) << 4));
      }
#pragma unroll
      for (int mi = 0; mi < FM; ++mi)
#pragma unroll
        for (int ni = 0; ni < FN; ++ni)
          acc[mi][ni] = __builtin_amdgcn_mfma_f32_16x16x32_f16(
              af[mi], bf[ni], acc[mi][ni], 0, 0, 0);
    }
    __syncthreads();
  }

#pragma unroll
  for (int mi = 0; mi < FM; ++mi) {
    const int r0 = m0 + wm * (FM * 16) + mi * 16 + ((lane >> 4) << 2);
#pragma unroll
    for (int ni = 0; ni < FN; ++ni) {
      const int cc = n0 + wn * (FN * 16) + ni * 16 + (lane & 15);
      const float bv = BIAS ? bias[cc] : 0.0f;
#pragma unroll
      for (int q = 0; q < 4; ++q)
        C[(size_t)(r0 + q) * LDC + cc] = acc[mi][ni][q] * scale + bv;
    }
  }
}

// ---------------------------------------------------------------------------
extern "C" void kernel_launch(void* const* d_in, const int* in_sizes, int n_in,
                              void* d_out, int out_size, void* d_ws, size_t ws_size,
                              hipStream_t stream) {
  const int*   x     = (const int*)  d_in[0];
  const float* embed = (const float*)d_in[1];
  const float* W1    = (const float*)d_in[2];
  const float* b1    = (const float*)d_in[3];
  const float* W2    = (const float*)d_in[4];
  const float* b2    = (const float*)d_in[5];
  const float* beta1 = (const float*)d_in[6];
  const float* thr1  = (const float*)d_in[7];
  const float* beta2 = (const float*)d_in[8];
  // d_in[9] = thr2: clipped but unused by the output
  float* out = (float*)d_out;

  char* ws = (char*)d_ws;
  float*    Tp     = (float*)   ws;                     // 16 MB [2][2048][1024]
  _Float16* Ap     = (_Float16*)(ws + (16u << 20));     //  4 MB [2048][1024]
  _Float16* Btp    = (_Float16*)(ws + (20u << 20));     //  2 MB [1024][1024]
  _Float16* W2T    = (_Float16*)(ws + (22u << 20));     //  2 MB [2048][512]
  _Float16* S      = (_Float16*)(ws + (24u << 20));     //  8 MB [8192][512]
  float*    bias2s = (float*)   (ws + (32u << 20));     //  8 KB

  prep_kernel<<<dim3(1416), 256, 0, stream>>>(embed, W1, W2, b2, beta2,
                                              Ap, Btp, W2T, bias2s);

  // Tp[z] = partial embed@W1 (f16 split, virtual K=1536, z-split x2)
  gemm1_kernel<<<dim3(256, 2), 256, 0, stream>>>(Ap, Btp, Tp);

  recur_kernel<<<dim3(2048), 256, 0, stream>>>(x, Tp, b1, beta1, thr1, beta2, S);

  // out = S @ W2 + cb*b2   (128x128 tile, 2x2 waves, 1024 blocks)
  mfma_gemm_kernel<128, 128, 2, 2, 512, 512, 2048, 8, 16, true>
      <<<dim3(1024), 256, 0, stream>>>(S, W2T, bias2s, out, 1.0f);
}

// Round 5
// 65.232 us; speedup vs baseline: 1.9400x; 1.0073x over previous
//
#include <hip/hip_runtime.h>
#include <hip/hip_bf16.h>
#include <stdint.h>

typedef float    f32x4 __attribute__((ext_vector_type(4)));
typedef _Float16 f16x4 __attribute__((ext_vector_type(4)));
typedef _Float16 f16x8 __attribute__((ext_vector_type(8)));

#define NSTEPS 15

// ---------------------------------------------------------------------------
// Fused prep kernel, block-range dispatch:
//   [0,1024)    split_e : embed [2048][512] f32 -> Ap [2048][1024] f16 = [e0|e1]
//   [1024,1152) w1t     : W1 [1024][512] f32 -> Btp [1024][1024] f16 (T, 64x, split)
//   [1152,1408) w2t     : W2 [512][2048] f32 -> W2T [2048][512] f16 (T)
//   [1408,1416) bias2   : bias2s[n] = (sum beta2^k) * b2[n]
// ---------------------------------------------------------------------------
__global__ __launch_bounds__(256) void prep_kernel(
    const float* __restrict__ embed, const float* __restrict__ W1,
    const float* __restrict__ W2, const float* __restrict__ b2,
    const float* __restrict__ beta2p,
    _Float16* __restrict__ Ap, _Float16* __restrict__ Btp,
    _Float16* __restrict__ W2T, float* __restrict__ bias2s)
{
  __shared__ _Float16 sh[2][64][72];
  const int b = blockIdx.x;
  const int t = threadIdx.x;

  if (b < 1024) {                       // ---- split_e (Dekker two-way split)
    const int i  = b * 256 + t;
    const int m  = i >> 7;
    const int k4 = (i & 127) * 4;
    f32x4 v = *(const f32x4*)&embed[(size_t)m * 512 + k4];
    f16x4 h0, h1;
#pragma unroll
    for (int j = 0; j < 4; ++j) {
      h0[j] = (_Float16)v[j];
      h1[j] = (_Float16)(v[j] - (float)h0[j]);
    }
    _Float16* r = Ap + (size_t)m * 1024 + k4;
    *(f16x4*)(r)       = h0;
    *(f16x4*)(r + 512) = h1;
  } else if (b < 1152) {                // ---- w1t_split (transpose + 64x + split)
    const int idx = b - 1024;
    const int n0 = (idx & 7) * 64;
    const int k0 = ((idx >> 3) & 7) * 64;
    const int z  = idx >> 6;
    const int kk = t >> 4;
    const int n4 = (t & 15) * 4;
#pragma unroll
    for (int i = 0; i < 4; ++i) {
      f32x4 v = *(const f32x4*)&W1[(size_t)(z * 512 + k0 + kk + i * 16) * 512 + n0 + n4];
#pragma unroll
      for (int j = 0; j < 4; ++j) {
        float s = v[j] * 64.0f;         // exact pow2 scale
        _Float16 hi = (_Float16)s;
        sh[0][n4 + j][kk + i * 16] = hi;
        sh[1][n4 + j][kk + i * 16] = (_Float16)(s - (float)hi);
      }
    }
    __syncthreads();
#pragma unroll
    for (int i = 0; i < 2; ++i) {
      const int nn = (t >> 3) + i * 32;
      const int k8 = (t & 7) * 8;
      _Float16* r = Btp + (size_t)(z * 512 + n0 + nn) * 1024 + k0 + k8;
      *(uint4*)(r)       = *(const uint4*)&sh[0][nn][k8];
      *(uint4*)(r + 512) = *(const uint4*)&sh[1][nn][k8];
    }
  } else if (b < 1408) {                // ---- w2t (transpose + f16 convert)
    const int idx = b - 1152;
    const int n0 = (idx & 31) * 64;
    const int k0 = (idx >> 5) * 64;
    const int kk = t >> 4;
    const int n4 = (t & 15) * 4;
#pragma unroll
    for (int i = 0; i < 4; ++i) {
      f32x4 v = *(const f32x4*)&W2[(size_t)(k0 + kk + i * 16) * 2048 + n0 + n4];
#pragma unroll
      for (int j = 0; j < 4; ++j) sh[0][n4 + j][kk + i * 16] = (_Float16)v[j];
    }
    __syncthreads();
#pragma unroll
    for (int i = 0; i < 2; ++i) {
      const int nn = (t >> 3) + i * 32;
      const int k8 = (t & 7) * 8;
      *(uint4*)&W2T[(size_t)(n0 + nn) * 512 + k0 + k8] = *(const uint4*)&sh[0][nn][k8];
    }
  } else {                              // ---- bias2
    const float beta2 = fminf(fmaxf(beta2p[0], 0.1f), 0.9f);
    float cb = 0.0f;
    for (int i = 0; i < NSTEPS; ++i) cb = beta2 * cb + 1.0f;
    const int n = (b - 1408) * 256 + t;
    if (n < 2048) bias2s[n] = cb * b2[n];
  }
}

// ---------------------------------------------------------------------------
__device__ __forceinline__ void gld_lds16(const void* g, void* l) {
  __builtin_amdgcn_global_load_lds(
      (const __attribute__((address_space(1))) uint32_t*)g,
      (__attribute__((address_space(3))) uint32_t*)l, 16, 0, 0);
}

// ---------------------------------------------------------------------------
// gemm1: Tp[z] = (1/64) * Ap @ Btp^T over virtual K-range [z*768,(z+1)*768)
// Virtual K=1536 = [e0w0 | e1w0 | e0w1] resolved via column maps.
// 128x64 tile, 4x1 waves, FM=2, FN=4. Grid (256, 2) -> 2 blocks/CU.
// ---------------------------------------------------------------------------
__global__ __launch_bounds__(256) void gemm1_kernel(
    const _Float16* __restrict__ Ap,   // [2048][1024]
    const _Float16* __restrict__ Btp,  // [1024][1024]
    float* __restrict__ Tp)            // [2][2048][1024]
{
  __shared__ __align__(16) char lds[(128 + 64) * 128];
  char* AsB = lds;              // 128 rows x 128B, XOR-swizzled 16B chunks
  char* BsB = lds + 128 * 128;  //  64 rows x 128B

  const int t    = threadIdx.x;
  const int lane = t & 63;
  const int wave = t >> 6;      // wm = wave (4x1), wn = 0
  const int z    = blockIdx.y;

  int bid = blockIdx.x;
  bid = (bid & 7) * 32 + (bid >> 3);   // XCD swizzle (256 % 8 == 0)
  const int m0 = (bid >> 4) * 128;     // 16 m-tiles
  const int n0 = (bid & 15) * 64;      // 16 n-tiles

  f32x4 acc[2][4] = {};

  for (int kt = 0; kt < 12; ++kt) {
    const int k0   = z * 768 + kt * 64;
    const int acol = (k0 < 1024) ? k0 : k0 - 1024;
    const int bcol = (k0 < 1024) ? (k0 & 511) : k0 - 512;
#pragma unroll
    for (int i = 0; i < 4; ++i) {      // A: 128 rows
      const int ob  = i * 4096 + wave * 1024;
      const int o   = ob + lane * 16;
      const int row = o >> 7;
      const int c   = ((o >> 4) & 7) ^ (row & 7);
      gld_lds16(Ap + ((size_t)(m0 + row) * 1024 + acol + c * 8), AsB + ob);
    }
#pragma unroll
    for (int i = 0; i < 2; ++i) {      // B: 64 rows
      const int ob  = i * 4096 + wave * 1024;
      const int o   = ob + lane * 16;
      const int row = o >> 7;
      const int c   = ((o >> 4) & 7) ^ (row & 7);
      gld_lds16(Btp + ((size_t)(n0 + row) * 1024 + bcol + c * 8), BsB + ob);
    }
    asm volatile("s_waitcnt vmcnt(0)" ::: "memory");
    __syncthreads();

#pragma unroll
    for (int kk = 0; kk < 2; ++kk) {
      const int lc = (lane >> 4) + kk * 4;
      f16x8 af[2], bf[4];
#pragma unroll
      for (int mi = 0; mi < 2; ++mi) {
        const int row = wave * 32 + mi * 16 + (lane & 15);
        af[mi] = *(const f16x8*)(AsB + row * 128 + ((lc ^ (row & 7)) << 4));
      }
#pragma unroll
      for (int ni = 0; ni < 4; ++ni) {
        const int row = ni * 16 + (lane & 15);
        bf[ni] = *(const f16x8*)(BsB + row * 128 + ((lc ^ (row & 7)) << 4));
      }
#pragma unroll
      for (int mi = 0; mi < 2; ++mi)
#pragma unroll
        for (int ni = 0; ni < 4; ++ni)
          acc[mi][ni] = __builtin_amdgcn_mfma_f32_16x16x32_f16(
              af[mi], bf[ni], acc[mi][ni], 0, 0, 0);
    }
    __syncthreads();
  }

  float* Cz = Tp + (size_t)z * 2048 * 1024;
#pragma unroll
  for (int mi = 0; mi < 2; ++mi) {
    const int r0 = m0 + wave * 32 + mi * 16 + ((lane >> 4) << 2);
#pragma unroll
    for (int ni = 0; ni < 4; ++ni) {
      const int cc = n0 + ni * 16 + (lane & 15);
#pragma unroll
      for (int q = 0; q < 4; ++q)
        Cz[(size_t)(r0 + q) * 1024 + cc] = acc[mi][ni][q] * 0.015625f;
    }
  }
}

// ---------------------------------------------------------------------------
// Per-element 15-step LIF recurrence -> weighted spike sums S [8192][512] f16
// ---------------------------------------------------------------------------
__global__ __launch_bounds__(256) void recur_kernel(
    const int* __restrict__ x,        // [8192][2]
    const float* __restrict__ Tp,     // [2][2048][1024]
    const float* __restrict__ b1,     // [512]
    const float* __restrict__ beta1p, const float* __restrict__ thr1p,
    const float* __restrict__ beta2p,
    _Float16* __restrict__ S)         // [8192][512]
{
  const float beta1 = fminf(fmaxf(beta1p[0], 0.1f), 0.9f);
  const float thr1  = fmaxf(thr1p[0], 0.1f);
  const float beta2 = fminf(fmaxf(beta2p[0], 0.1f), 0.9f);
  const size_t ZS = (size_t)2048 * 1024;

  const int t = threadIdx.x;
  const int b = blockIdx.x * 4 + (t >> 6);
  const int h = (t & 63) * 8;
  const int x0 = x[b * 2 + 0];
  const int x1 = x[b * 2 + 1];

  const float* p00 = &Tp[(size_t)x0 * 1024 + h];
  const float* p01 = &Tp[(size_t)x1 * 1024 + 512 + h];

  float cur[8];
#pragma unroll
  for (int half = 0; half < 2; ++half) {
    f32x4 a0 = *(const f32x4*)(p00 + half * 4);
    f32x4 a1 = *(const f32x4*)(p00 + ZS + half * 4);
    f32x4 c0 = *(const f32x4*)(p01 + half * 4);
    f32x4 c1 = *(const f32x4*)(p01 + ZS + half * 4);
    f32x4 e  = *(const f32x4*)&b1[h + half * 4];
#pragma unroll
    for (int j = 0; j < 4; ++j)
      cur[half * 4 + j] = (a0[j] + a1[j]) + (c0[j] + c1[j]) + e[j];
  }

  float m[8] = {}, s[8] = {};
#pragma unroll
  for (int st = 0; st < NSTEPS; ++st) {
#pragma unroll
    for (int j = 0; j < 8; ++j) {
      // reset uses PREVIOUS mem; spike uses UPDATED mem (snntorch Leaky, subtract)
      float r = (m[j] > thr1) ? thr1 : 0.0f;
      m[j] = beta1 * m[j] + cur[j] - r;
      float sp = (m[j] > thr1) ? 1.0f : 0.0f;
      s[j] = beta2 * s[j] + sp;   // S = sum_t beta2^{15-t} spk_t
    }
  }

  __align__(16) _Float16 o[8];
#pragma unroll
  for (int j = 0; j < 8; ++j) o[j] = (_Float16)s[j];
  *(uint4*)&S[(size_t)b * 512 + h] = *(const uint4*)o;
}

// ---------------------------------------------------------------------------
// gemm2 (deep-pipelined): out[8192][2048] = S @ W2T^T + bias2s
// 256x128 tile, BK=64, 8 waves (2M x 4N, per-wave 128x32), 512 threads.
// 3-deep LDS ring (3 x 48KB): tile T(t+2) staged into buf((t+2)%3) DURING
// window(T(t)) -- two windows before first read. One vmcnt(6) per window
// (counted, never 0): guarantees T(t+1) resident, leaves this window's 6
// stage-loads in flight. Raw s_barrier (no drain). setprio around MFMA (T5).
// Accumulation order identical to the 2-phase kernel (bitwise-same result).
// ---------------------------------------------------------------------------
__device__ __forceinline__ void g2_round(
    const _Float16* __restrict__ A, const _Float16* __restrict__ Bt,
    char* lds, int m0, int n0, int wave, int lane, int tile, int r)
{
  const int k0 = tile * 64;
  char* lb = lds + (tile % 3) * 49152;
  if (r < 4) {                       // A rounds: 256 rows x 128B
    const int ob  = r * 8192 + wave * 1024;
    const int o   = ob + lane * 16;
    const int row = o >> 7;
    const int c   = ((o >> 4) & 7) ^ (row & 7);
    gld_lds16(A + ((size_t)(m0 + row) * 512 + k0 + c * 8), lb + ob);
  } else {                           // B rounds: 128 rows x 128B
    const int ob  = (r - 4) * 8192 + wave * 1024;
    const int o   = ob + lane * 16;
    const int row = o >> 7;
    const int c   = ((o >> 4) & 7) ^ (row & 7);
    gld_lds16(Bt + ((size_t)(n0 + row) * 512 + k0 + c * 8), lb + 32768 + ob);
  }
}

template<int QA>
__device__ __forceinline__ void g2_mfma16(
    f32x4 (&acc)[8][2], const f16x8 (&af)[4][2], const f16x8 (&bf)[2][2])
{
#pragma unroll
  for (int kk = 0; kk < 2; ++kk)
#pragma unroll
    for (int mi = 0; mi < 4; ++mi)
#pragma unroll
      for (int ni = 0; ni < 2; ++ni)
        acc[QA * 4 + mi][ni] = __builtin_amdgcn_mfma_f32_16x16x32_f16(
            af[mi][kk], bf[ni][kk], acc[QA * 4 + mi][ni], 0, 0, 0);
}

template<int QA>
__device__ __forceinline__ void g2_lda(
    f16x8 (&af)[4][2], const char* lb, int wm, int lane)
{
#pragma unroll
  for (int mi = 0; mi < 4; ++mi) {
    const int row = wm * 128 + QA * 64 + mi * 16 + (lane & 15);
#pragma unroll
    for (int kk = 0; kk < 2; ++kk) {
      const int lc = (lane >> 4) + kk * 4;
      af[mi][kk] = *(const f16x8*)(lb + row * 128 + ((lc ^ (row & 7)) << 4));
    }
  }
}

__device__ __forceinline__ void g2_ldb(
    f16x8 (&bf)[2][2], const char* lb, int wn, int lane)
{
#pragma unroll
  for (int ni = 0; ni < 2; ++ni) {
    const int row = wn * 32 + ni * 16 + (lane & 15);
#pragma unroll
    for (int kk = 0; kk < 2; ++kk) {
      const int lc = (lane >> 4) + kk * 4;
      bf[ni][kk] = *(const f16x8*)(lb + 32768 + row * 128 + ((lc ^ (row & 7)) << 4));
    }
  }
}

__global__ __launch_bounds__(512, 2) void gemm2_pipe_kernel(
    const _Float16* __restrict__ A,    // S   [8192][512]
    const _Float16* __restrict__ Bt,   // W2T [2048][512]
    const float* __restrict__ bias,    // [2048]
    float* __restrict__ C)             // [8192][2048]
{
  __shared__ __align__(16) char lds[3 * 49152];   // 144 KB

  const int t    = threadIdx.x;
  const int lane = t & 63;
  const int wave = t >> 6;
  const int wm   = wave >> 2;   // 0..1
  const int wn   = wave & 3;    // 0..3

  int bid = blockIdx.x;
  bid = (bid & 7) * 64 + (bid >> 3);   // XCD swizzle (512 % 8 == 0)
  const int m0 = (bid >> 4) * 256;     // 32 m-tiles
  const int n0 = (bid & 15) * 128;     // 16 n-tiles

  f32x4 acc[8][2] = {};
  f16x8 af[4][2], bf[2][2];

  // prologue: T0, T1 fully staged; vmcnt(6) -> T0 resident, T1 may be in flight
#pragma unroll
  for (int r = 0; r < 6; ++r) g2_round(A, Bt, lds, m0, n0, wave, lane, 0, r);
#pragma unroll
  for (int r = 0; r < 6; ++r) g2_round(A, Bt, lds, m0, n0, wave, lane, 1, r);
  asm volatile("s_waitcnt vmcnt(6)" ::: "memory");
  __builtin_amdgcn_s_barrier();

  for (int tt = 0; tt < 8; ++tt) {
    const char* lb = lds + (tt % 3) * 49152;
    const bool pf = (tt + 2 < 8);

    // ---- phase qa=0: ds-read A-half0 + B, stage rounds 0-2 of T(tt+2)
    g2_lda<0>(af, lb, wm, lane);
    g2_ldb(bf, lb, wn, lane);
    if (pf) {
      g2_round(A, Bt, lds, m0, n0, wave, lane, tt + 2, 0);
      g2_round(A, Bt, lds, m0, n0, wave, lane, tt + 2, 1);
      g2_round(A, Bt, lds, m0, n0, wave, lane, tt + 2, 2);
    }
    __builtin_amdgcn_s_barrier();
    asm volatile("s_waitcnt lgkmcnt(0)" ::: "memory");
    __builtin_amdgcn_s_setprio(1);
    g2_mfma16<0>(acc, af, bf);
    __builtin_amdgcn_s_setprio(0);
    __builtin_amdgcn_s_barrier();

    // ---- phase qa=1: ds-read A-half1 (reuse B), stage rounds 3-5 of T(tt+2)
    g2_lda<1>(af, lb, wm, lane);
    if (pf) {
      g2_round(A, Bt, lds, m0, n0, wave, lane, tt + 2, 3);
      g2_round(A, Bt, lds, m0, n0, wave, lane, tt + 2, 4);
      g2_round(A, Bt, lds, m0, n0, wave, lane, tt + 2, 5);
    }
    __builtin_amdgcn_s_barrier();
    asm volatile("s_waitcnt lgkmcnt(0)" ::: "memory");
    __builtin_amdgcn_s_setprio(1);
    g2_mfma16<1>(acc, af, bf);
    __builtin_amdgcn_s_setprio(0);
    // counted drain: forces previous window's rounds (T(tt+1)) complete;
    // leaves this window's 6 rounds (T(tt+2)) in flight.
    asm volatile("s_waitcnt vmcnt(6)" ::: "memory");
    __builtin_amdgcn_s_barrier();
  }

  // epilogue: C/D layout col=lane&15, row=(lane>>4)*4+reg
#pragma unroll
  for (int a = 0; a < 8; ++a) {
    const int r0 = m0 + wm * 128 + a * 16 + ((lane >> 4) << 2);
#pragma unroll
    for (int ni = 0; ni < 2; ++ni) {
      const int cc = n0 + wn * 32 + ni * 16 + (lane & 15);
      const float bv = bias[cc];
#pragma unroll
      for (int q = 0; q < 4; ++q)
        C[(size_t)(r0 + q) * 2048 + cc] = acc[a][ni][q] + bv;
    }
  }
}

// ---------------------------------------------------------------------------
extern "C" void kernel_launch(void* const* d_in, const int* in_sizes, int n_in,
                              void* d_out, int out_size, void* d_ws, size_t ws_size,
                              hipStream_t stream) {
  const int*   x     = (const int*)  d_in[0];
  const float* embed = (const float*)d_in[1];
  const float* W1    = (const float*)d_in[2];
  const float* b1    = (const float*)d_in[3];
  const float* W2    = (const float*)d_in[4];
  const float* b2    = (const float*)d_in[5];
  const float* beta1 = (const float*)d_in[6];
  const float* thr1  = (const float*)d_in[7];
  const float* beta2 = (const float*)d_in[8];
  // d_in[9] = thr2: clipped but unused by the output
  float* out = (float*)d_out;

  char* ws = (char*)d_ws;
  float*    Tp     = (float*)   ws;                     // 16 MB [2][2048][1024]
  _Float16* Ap     = (_Float16*)(ws + (16u << 20));     //  4 MB [2048][1024]
  _Float16* Btp    = (_Float16*)(ws + (20u << 20));     //  2 MB [1024][1024]
  _Float16* W2T    = (_Float16*)(ws + (22u << 20));     //  2 MB [2048][512]
  _Float16* S      = (_Float16*)(ws + (24u << 20));     //  8 MB [8192][512]
  float*    bias2s = (float*)   (ws + (32u << 20));     //  8 KB

  prep_kernel<<<dim3(1416), 256, 0, stream>>>(embed, W1, W2, b2, beta2,
                                              Ap, Btp, W2T, bias2s);

  // Tp[z] = partial embed@W1 (f16 split, virtual K=1536, z-split x2)
  gemm1_kernel<<<dim3(256, 2), 256, 0, stream>>>(Ap, Btp, Tp);

  recur_kernel<<<dim3(2048), 256, 0, stream>>>(x, Tp, b1, beta1, thr1, beta2, S);

  // out = S @ W2 + cb*b2  (256x128 tile, 3-deep pipeline, counted vmcnt)
  gemm2_pipe_kernel<<<dim3(512), 512, 0, stream>>>(S, W2T, bias2s, out);
}